// Round 5
// baseline (212.628 us; speedup 1.0000x reference)
//
#include <hip/hip_runtime.h>

#define NN   4096
#define KNBR 8
#define DF   240
#define SUBW 8    // candidate sub-ranges (waves) per kNN block
#define QPB  64   // queries per kNN block
#define NQRT 4    // candidate quarters

// Distance-only sorted-top-8 insert: pure med3/min chain, NO masks, NO bools.
__device__ __forceinline__ void insD(float v, float t[KNBR]) {
#pragma unroll
  for (int k = KNBR - 1; k >= 1; k--)
    t[k] = __builtin_amdgcn_fmed3f(t[k - 1], t[k], v);
  t[0] = fminf(t[0], v);
}

// (distance,index) sorted-top-8 insert — proven formulation:
__device__ __forceinline__ void insertDI(float d2, int j, float bd[KNBR],
                                         int bi[KNBR]) {
#pragma unroll
  for (int k = KNBR - 1; k >= 1; k--) {
    bool mk  = d2 < bd[k];
    bool mk1 = d2 < bd[k - 1];
    bd[k] = mk ? (mk1 ? bd[k - 1] : d2) : bd[k];
    bi[k] = mk ? (mk1 ? bi[k - 1] : j) : bi[k];
  }
  bool m0 = d2 < bd[0];
  bd[0] = m0 ? d2 : bd[0];
  bi[0] = m0 ? j : bi[0];
}

// ---------------------------------------------------------------------------
// Kernel 1: kNN pass 1 (per-sub TOP-2 distances) ⊕ weight fusion.
//   blocks [0,1024): per-(query,quarter,sub) top-2 distances -> qd (64/query).
//     R5: top-2 instead of top-8 (2 VALU insert vs 8). Validity: qd is a
//     SUBSET of all distances, so its 8th-smallest (thr) >= true 8th ->
//     collect admits a superset of the true top-8; collect stays exact.
//     No pd LDS, no barrier-merge, no serial tail. Candidates staged SoA;
//     hot loop reads 4 candidates per 3 ds_read_b128.
//   blocks [1024,1034): fuse weights, stored TRANSPOSED for float4 epilogue:
//     WAT[64x32] @0 | WBT[32x64] @2048 | WCT[32x16] @4096 | WDT[16x32] @4608
// ---------------------------------------------------------------------------
__global__ __launch_bounds__(512) void knn_scan_fuse(
    const float* __restrict__ coords, float* __restrict__ qd,
    const float* __restrict__ W1, const float* __restrict__ W2,
    const float* __restrict__ W3, const float* __restrict__ W4,
    const float* __restrict__ L0, const float* __restrict__ L1,
    const float* __restrict__ L2, float* __restrict__ Wf) {
  if (blockIdx.x >= 1024) {            // -------- weight-fusion blocks
    const float sA = 0.012757759076995719f;  // sqrt(1/96)/8
    const float sB = 0.019764235376052370f;  // 1/sqrt(80*32)
    const float sC = 0.034232659844072875f;  // sqrt(3)/sqrt(80*32)
    const float sD = 0.098821176880261850f;  // sqrt(5/32)/4
    int idx = (blockIdx.x - 1024) * 512 + threadIdx.x;  // [0,5120)
    if (idx < 2048) {                       // WA = W2(32x64)@L0(64x64)
      int u = idx >> 6, c = idx & 63;
      float a = 0.f;
#pragma unroll 8
      for (int m = 0; m < 64; m++) a += W2[u * 64 + m] * L0[m * 64 + c];
      Wf[c * 32 + u] = sA * a;              // WAT[c][u]
    } else if (idx < 4096) {                // WB = W1(64x32)@L1(32x32)
      int t = idx - 2048;
      int u = t >> 5, c = t & 31;
      float a = 0.f;
#pragma unroll 8
      for (int m = 0; m < 32; m++) a += W1[u * 32 + m] * L1[m * 32 + c];
      Wf[2048 + c * 64 + u] = sB * a;       // WBT[c][u]
    } else if (idx < 4608) {                // WC = W4(16x32)@L1(32x32)
      int t = idx - 4096;
      int u = t >> 5, c = t & 31;
      float a = 0.f;
#pragma unroll 8
      for (int m = 0; m < 32; m++) a += W4[u * 32 + m] * L1[m * 32 + c];
      Wf[4096 + c * 16 + u] = sC * a;       // WCT[c][u]
    } else {                                // WD = W3(32x16)@L2(16x16)
      int t = idx - 4608;
      int u = t >> 4, c = t & 15;
      float a = 0.f;
#pragma unroll 8
      for (int m = 0; m < 16; m++) a += W3[u * 16 + m] * L2[m * 16 + c];
      Wf[4608 + c * 32 + u] = sD * a;       // WDT[c][u]
    }
    return;
  }

  // -------- pass-1 distance scan, SoA candidates, top-2 per sub
  __shared__ float cx[1024], cy[1024], cz[1024];   // 12 KB
  const int blk = blockIdx.x;
  const int b = blk >> 8;
  const int chunk = (blk >> 2) & 63;
  const int quarter = blk & 3;
  const int qi  = threadIdx.x & 63;
  const int sub = threadIdx.x >> 6;
  const int iq  = chunk * 64 + qi;
  const float* cb = coords + (size_t)b * NN * 3;

  {  // SoA stage: thread t repacks candidates 2t, 2t+1 (in-bounds, coalesced)
    int t = threadIdx.x;
    const float* s = cb + quarter * 3072 + t * 6;
    float v0 = s[0], v1 = s[1], v2 = s[2], v3 = s[3], v4 = s[4], v5 = s[5];
    cx[2 * t] = v0; cy[2 * t] = v1; cz[2 * t] = v2;
    cx[2 * t + 1] = v3; cy[2 * t + 1] = v4; cz[2 * t + 1] = v5;
  }
  const float qx = cb[iq * 3 + 0], qy = cb[iq * 3 + 1], qz = cb[iq * 3 + 2];
  __syncthreads();

  float t0v = 3.0e38f, t1v = 3.0e38f;
  const int j0 = quarter * 1024;
  const int c0 = sub * 128;
#pragma unroll 4
  for (int g4 = 0; g4 < 32; ++g4) {
    int ci = c0 + 4 * g4;
    float4 X = *(const float4*)&cx[ci];
    float4 Y = *(const float4*)&cy[ci];
    float4 Z = *(const float4*)&cz[ci];
    float xs[4] = {X.x, X.y, X.z, X.w};
    float ys[4] = {Y.x, Y.y, Y.z, Y.w};
    float zs[4] = {Z.x, Z.y, Z.z, Z.w};
#pragma unroll
    for (int c = 0; c < 4; ++c) {
      float dx = xs[c] - qx, dy = ys[c] - qy, dz = zs[c] - qz;
      float d2 = dx * dx + dy * dy + dz * dz;
      d2 = (j0 + ci + c == iq) ? 3.0e38f : d2;   // exclude self
      t1v = __builtin_amdgcn_fmed3f(t0v, t1v, d2);
      t0v = fminf(t0v, d2);
    }
  }
  size_t qbase = (size_t)(b * NN + iq) * 64 + quarter * 16 + sub * 2;
  qd[qbase + 0] = t0v;
  qd[qbase + 1] = t1v;
}

// ---------------------------------------------------------------------------
// Kernel 2: per-query threshold = 8th smallest of the 64 stored top-2 values
// (valid upper bound on the true 8th-smallest distance).
// ---------------------------------------------------------------------------
__global__ __launch_bounds__(256) void knn_thr(
    const float* __restrict__ qd, float* __restrict__ thr) {
  int g = blockIdx.x * 256 + threadIdx.x;   // global query id
  float md[KNBR];
#pragma unroll
  for (int k = 0; k < KNBR; k++) md[k] = 3.0e38f;
  const float4* q4 = (const float4*)(qd + (size_t)g * 64);
#pragma unroll
  for (int i = 0; i < 16; i++) {
    float4 v = q4[i];
    insD(v.x, md); insD(v.y, md); insD(v.z, md); insD(v.w, md);
  }
  thr[g] = md[KNBR - 1];
}

// ---------------------------------------------------------------------------
// Kernel 3: collect (pass 2). SoA candidates from LDS; only d2 <= thr enters
// the guarded insertDI. Writes per-(query,quarter) sorted (d, local j) top-8.
// Output aliases the qd buffer (collect never reads qd; thr already did).
// Exactness: {d2<=thr} contains the top-8 set incl. ties; ascending-j
// strict-< insertion matches the reference stable top_k tie-break.
// ---------------------------------------------------------------------------
__global__ __launch_bounds__(512) void knn_collect(
    const float* __restrict__ coords, const float* __restrict__ thr,
    float* __restrict__ qd2, int* __restrict__ qj2) {
  __shared__ float pd[SUBW][QPB][KNBR + 1];        // stride-9 pad
  __shared__ int   pi[SUBW][QPB][KNBR + 1];
  __shared__ float cx[1024], cy[1024], cz[1024];   // 12 KB
  const int blk = blockIdx.x;
  const int b = blk >> 8;
  const int chunk = (blk >> 2) & 63;
  const int quarter = blk & 3;
  const int qi  = threadIdx.x & 63;
  const int sub = threadIdx.x >> 6;
  const int iq  = chunk * 64 + qi;
  const float* cb = coords + (size_t)b * NN * 3;

  {
    int t = threadIdx.x;
    const float* s = cb + quarter * 3072 + t * 6;
    float v0 = s[0], v1 = s[1], v2 = s[2], v3 = s[3], v4 = s[4], v5 = s[5];
    cx[2 * t] = v0; cy[2 * t] = v1; cz[2 * t] = v2;
    cx[2 * t + 1] = v3; cy[2 * t + 1] = v4; cz[2 * t + 1] = v5;
  }
  const float qx = cb[iq * 3 + 0], qy = cb[iq * 3 + 1], qz = cb[iq * 3 + 2];
  const float tq = thr[b * NN + iq];
  __syncthreads();

  float bd[KNBR];
  int bi[KNBR];
#pragma unroll
  for (int k = 0; k < KNBR; k++) { bd[k] = 3.0e38f; bi[k] = 0; }
  const int j0 = quarter * 1024;
  const int c0 = sub * 128;
#pragma unroll 2
  for (int g4 = 0; g4 < 32; ++g4) {
    int ci = c0 + 4 * g4;
    float4 X = *(const float4*)&cx[ci];
    float4 Y = *(const float4*)&cy[ci];
    float4 Z = *(const float4*)&cz[ci];
    float xs[4] = {X.x, X.y, X.z, X.w};
    float ys[4] = {Y.x, Y.y, Y.z, Y.w};
    float zs[4] = {Z.x, Z.y, Z.z, Z.w};
#pragma unroll
    for (int c = 0; c < 4; ++c) {
      int jj = j0 + ci + c;
      float dx = xs[c] - qx, dy = ys[c] - qy, dz = zs[c] - qz;
      float d2 = dx * dx + dy * dy + dz * dz;
      d2 = (jj == iq) ? 3.0e38f : d2;
      if (d2 <= tq) insertDI(d2, jj, bd, bi);   // rare path
    }
  }
#pragma unroll
  for (int k = 0; k < KNBR; k++) {
    pd[sub][qi][k] = bd[k];
    pi[sub][qi][k] = bi[k];
  }
  __syncthreads();
  if (threadIdx.x < 64) {
    float md[KNBR];
    int mi[KNBR];
#pragma unroll
    for (int k = 0; k < KNBR; k++) { md[k] = 3.0e38f; mi[k] = 0; }
    for (int s = 0; s < SUBW; s++) {
#pragma unroll
      for (int k = 0; k < KNBR; k++) {
        float vd = pd[s][qi][k];
        if (vd < md[KNBR - 1]) insertDI(vd, pi[s][qi][k], md, mi);
      }
    }
    size_t base = ((size_t)(b * NN + iq) * NQRT + quarter) * KNBR;
#pragma unroll
    for (int k = 0; k < KNBR; k++) {
      qd2[base + k] = md[k];
      qj2[base + k] = mi[k];   // batch-local index (sentinel = (3e38, 0))
    }
  }
}

// ---------------------------------------------------------------------------
// Kernel 4: merge-fold + gather + moments + fused weights + output.
// One wave per node; 4 nodes/block. (256,4): no spills (R2 lesson).
// XCD chunked swizzle (T1), bijective (4096 % 8 == 0).
//
// Merge fold: lanes 0..31 hold the 4 per-quarter sorted (d, j) 8-lists.
// Exact rank by lex (d, j, lane) == reference stable top_k tie-break;
// lane term only disambiguates (3e38,0) sentinels (always rank >= 8).
//
// R5: epilogue uses TRANSPOSED fused weights -> float4 global loads
// (256 -> 64 VMEM instrs) and float4 ds reads for y0's A row.
//
// Moments per node (432 floats in LDS):
//   S1[32] @0 | Z0[64][3] @32 | P[32][5] @224 | Q[16][3] @384
// ---------------------------------------------------------------------------
__global__ __launch_bounds__(256, 4) void msg_kernel(
    const float* __restrict__ feats, const float* __restrict__ coords,
    const float* __restrict__ qd2, const int* __restrict__ qj2,
    const float* __restrict__ Wf, float* __restrict__ out) {
  __shared__ float accb[4][432];
  __shared__ float sev[4][KNBR][3];
  __shared__ int snb[4][KNBR];

  const int bid = ((blockIdx.x & 7) << 9) | (blockIdx.x >> 3);  // XCD chunks
  const int w = threadIdx.x >> 6;   // wave within block -> node slot
  const int u = threadIdx.x & 63;   // lane
  const int node = bid * 4 + w;
  const int b = node >> 12;

  // ---- folded knn_merge: all-pairs rank select over 32 (d, j) pairs
  float dmy = 3.0e38f;
  int jmy = 0x7FFFFFFF;
  if (u < 32) {
    dmy = qd2[(size_t)node * 32 + u];
    jmy = qj2[(size_t)node * 32 + u];
  }
  int rank = 0;
#pragma unroll
  for (int m = 0; m < 32; m++) {
    float dm = __shfl(dmy, m);      // uniform m -> v_readlane
    int jm = __shfl(jmy, m);
    bool less = (dm < dmy) ||
                (dm == dmy && (jm < jmy || (jm == jmy && m < u)));
    rank += less ? 1 : 0;
  }
  if (u < 32 && rank < KNBR) {
    int jg = b * NN + jmy;          // batch-local -> global node id
    snb[w][rank] = jg;
    sev[w][rank][0] = coords[(size_t)jg * 3 + 0] - coords[(size_t)node * 3 + 0];
    sev[w][rank][1] = coords[(size_t)jg * 3 + 1] - coords[(size_t)node * 3 + 1];
    sev[w][rank][2] = coords[(size_t)jg * 3 + 2] - coords[(size_t)node * 3 + 2];
  }
  __syncthreads();

  const float S_ = 0.31622776601683794f;  // 1/sqrt(10)
  const float T_ = 0.18257418583505536f;  // 1/sqrt(30)

  float z0x = 0.f, z0y = 0.f, z0z = 0.f;
  float s1 = 0.f, p0 = 0.f, p1 = 0.f, p2 = 0.f, p3 = 0.f, p4 = 0.f;
  float q0 = 0.f, q1 = 0.f, q2 = 0.f;

#pragma unroll
  for (int h = 0; h < 2; h++) {
    // ---- prefetch chunk of 4 neighbor rows into registers
    const float* fr[4];
    float xv[4], av0[4], av1[4], av2[4];
    float bv0[4], bv1[4], bv2[4], bv3[4], bv4[4];
#pragma unroll
    for (int i = 0; i < 4; i++) {
      fr[i] = feats + (size_t)snb[w][4 * h + i] * DF;
      xv[i] = fr[i][u];
    }
    if (u < 32) {
#pragma unroll
      for (int i = 0; i < 4; i++) {
        av0[i] = fr[i][64 + 3 * u];
        av1[i] = fr[i][65 + 3 * u];
        av2[i] = fr[i][66 + 3 * u];
      }
      if (u < 16) {
#pragma unroll
        for (int i = 0; i < 4; i++) {
          bv0[i] = fr[i][160 + 5 * u];
          bv1[i] = fr[i][161 + 5 * u];
          bv2[i] = fr[i][162 + 5 * u];
          bv3[i] = fr[i][163 + 5 * u];
          bv4[i] = fr[i][164 + 5 * u];
        }
      }
    }
    // ---- consume chunk
#pragma unroll
    for (int i = 0; i < 4; i++) {
      const int e = 4 * h + i;
      float X = sev[w][e][0], Y = sev[w][e][1], Z = sev[w][e][2];
      float sxv = S_ * X, syv = S_ * Y, szv = S_ * Z;
      float txv = T_ * X, tyv = T_ * Y, t2z = 2.f * T_ * Z;
      z0x += xv[i] * X;
      z0y += xv[i] * Y;
      z0z += xv[i] * Z;
      if (u < 32) {
        s1 += av0[i] * X + av1[i] * Y + av2[i] * Z;
        p0 += av0[i] * syv + av1[i] * sxv;
        p1 += av0[i] * szv + av2[i] * sxv;
        p2 += av1[i] * szv + av2[i] * syv;
        p3 += av0[i] * sxv - av1[i] * syv;
        p4 += av2[i] * t2z - av0[i] * txv - av1[i] * tyv;
        if (u < 16) {
          q0 += bv0[i] * syv + bv1[i] * szv + bv3[i] * sxv - bv4[i] * txv;
          q1 += bv0[i] * sxv + bv2[i] * szv - bv3[i] * syv - bv4[i] * tyv;
          q2 += bv1[i] * sxv + bv2[i] * syv + bv4[i] * t2z;
        }
      }
    }
  }

  float* A = accb[w];
  A[32 + 3 * u + 0] = z0x;
  A[32 + 3 * u + 1] = z0y;
  A[32 + 3 * u + 2] = z0z;
  if (u < 32) {
    A[u] = s1;
    float* pp = A + 224 + 5 * u;
    pp[0] = p0; pp[1] = p1; pp[2] = p2; pp[3] = p3; pp[4] = p4;
  }
  if (u < 16) {
    float* qq = A + 384 + 3 * u;
    qq[0] = q0; qq[1] = q1; qq[2] = q2;
  }
  __syncthreads();

  float* orow = out + (size_t)node * DF;

  // y0[u] = sum_m S1[m] * WAT[u][m]  (float4 x 8, both sides)
  {
    float a = 0.f;
    const float4* A4 = (const float4*)A;             // S1[0..31]
    const float4* w4 = (const float4*)(Wf + u * 32); // WAT row u
#pragma unroll
    for (int m4 = 0; m4 < 8; m4++) {
      float4 av = A4[m4], wv = w4[m4];
      a += av.x * wv.x + av.y * wv.y + av.z * wv.z + av.w * wv.w;
    }
    orow[u] = a;
  }
  // y1 flat [w1*3+k], 96 outputs (two passes over 64 lanes)
#pragma unroll
  for (int m0 = 0; m0 < 96; m0 += 64) {
    int m = m0 + u;
    if (m < 96) {
      int w1 = m / 3, k = m - w1 * 3;
      float a = 0.f;
      const float4* wb4 = (const float4*)(Wf + 2048 + w1 * 64);  // WBT row
#pragma unroll
      for (int t4 = 0; t4 < 16; t4++) {
        float4 wv = wb4[t4];
        a += A[32 + 3 * (4 * t4 + 0) + k] * wv.x +
             A[32 + 3 * (4 * t4 + 1) + k] * wv.y +
             A[32 + 3 * (4 * t4 + 2) + k] * wv.z +
             A[32 + 3 * (4 * t4 + 3) + k] * wv.w;
      }
      const float4* wc4 = (const float4*)(Wf + 4096 + w1 * 16);  // WCT row
#pragma unroll
      for (int t4 = 0; t4 < 4; t4++) {
        float4 wv = wc4[t4];
        a += A[384 + 3 * (4 * t4 + 0) + k] * wv.x +
             A[384 + 3 * (4 * t4 + 1) + k] * wv.y +
             A[384 + 3 * (4 * t4 + 2) + k] * wv.z +
             A[384 + 3 * (4 * t4 + 3) + k] * wv.w;
      }
      orow[64 + m] = a;
    }
  }
  // y2 flat [w2*5+k], 80 outputs (two passes over 64 lanes)
#pragma unroll
  for (int m0 = 0; m0 < 80; m0 += 64) {
    int m = m0 + u;
    if (m < 80) {
      int w2 = m / 5, k = m - w2 * 5;
      float a = 0.f;
      const float4* wd4 = (const float4*)(Wf + 4608 + w2 * 32);  // WDT row
#pragma unroll
      for (int t4 = 0; t4 < 8; t4++) {
        float4 wv = wd4[t4];
        a += A[224 + 5 * (4 * t4 + 0) + k] * wv.x +
             A[224 + 5 * (4 * t4 + 1) + k] * wv.y +
             A[224 + 5 * (4 * t4 + 2) + k] * wv.z +
             A[224 + 5 * (4 * t4 + 3) + k] * wv.w;
      }
      orow[160 + m] = a;
    }
  }
}

// ---------------------------------------------------------------------------
extern "C" void kernel_launch(void* const* d_in, const int* in_sizes, int n_in,
                              void* d_out, int out_size, void* d_ws,
                              size_t ws_size, hipStream_t stream) {
  const float* feats  = (const float*)d_in[0];
  const float* coords = (const float*)d_in[1];
  const float* W1 = (const float*)d_in[2];
  const float* W2 = (const float*)d_in[3];
  const float* W3 = (const float*)d_in[4];
  const float* W4 = (const float*)d_in[5];
  const float* L0 = (const float*)d_in[6];
  const float* L1 = (const float*)d_in[7];
  const float* L2 = (const float*)d_in[8];
  float* out = (float*)d_out;

  // workspace (floats): Wf[5120] | qd[1048576] | thr[16384]  -> ~4.3 MB
  // collect's outputs alias qd: qd2 = qd[0..524288), qj2 = qd[524288..1048576)
  // (collect never reads qd; thr has already consumed it).
  float* Wf  = (float*)d_ws;
  float* qd  = (float*)d_ws + 5120;
  float* thr = (float*)d_ws + 5120 + 1048576;
  float* qd2 = qd;
  int*   qj2 = (int*)(qd + 524288);

  knn_scan_fuse<<<1034, 512, 0, stream>>>(coords, qd, W1, W2, W3, W4, L0, L1,
                                          L2, Wf);
  knn_thr<<<64, 256, 0, stream>>>(qd, thr);
  knn_collect<<<1024, 512, 0, stream>>>(coords, thr, qd2, qj2);
  msg_kernel<<<4096, 256, 0, stream>>>(feats, coords, qd2, qj2, Wf, out);
}

// Round 6
// 196.034 us; speedup vs baseline: 1.0846x; 1.0846x over previous
//
#include <hip/hip_runtime.h>

#define NN   4096
#define KNBR 8
#define DF   240
#define NSUB 16   // candidate sub-ranges (waves) per kNN block
#define QPB  64   // queries per kNN block

// Distance-only sorted-top-8 insert: pure med3/min chain.
__device__ __forceinline__ void insD(float v, float t[KNBR]) {
#pragma unroll
  for (int k = KNBR - 1; k >= 1; k--)
    t[k] = __builtin_amdgcn_fmed3f(t[k - 1], t[k], v);
  t[0] = fminf(t[0], v);
}

// (distance,index) sorted-top-8 insert — proven formulation:
__device__ __forceinline__ void insertDI(float d2, int j, float bd[KNBR],
                                         int bi[KNBR]) {
#pragma unroll
  for (int k = KNBR - 1; k >= 1; k--) {
    bool mk  = d2 < bd[k];
    bool mk1 = d2 < bd[k - 1];
    bd[k] = mk ? (mk1 ? bd[k - 1] : d2) : bd[k];
    bi[k] = mk ? (mk1 ? bi[k - 1] : j) : bi[k];
  }
  bool m0 = d2 < bd[0];
  bd[0] = m0 ? d2 : bd[0];
  bi[0] = m0 ? j : bi[0];
}

// ---------------------------------------------------------------------------
// Kernel 1: the ENTIRE kNN in one kernel ⊕ weight fusion.
//   blocks [0,256): block = (batch, 64-query chunk). 16 waves, each owning a
//     256-candidate sub-range; lane = query.
//       pass 1: per-sub top-2 distances -> LDS  (2 VALU/cand insert)
//       thr:    8th smallest of the 32 top-2 values (threads<64). Valid:
//               any SUBSET's 8th-smallest >= true 8th -> collect admits a
//               superset; collect stays exact.
//       pass 2: guarded exact insertDI (d2 <= thr rare) -> per-sub top-8
//       merge:  ascending sub = ascending j, strict-< insertion ==
//               reference stable top_k tie-break. Sentinels (3e38) never
//               insert (strict <). Writes final 8 GLOBAL neighbor ids.
//     Candidates read straight from global (192 KB total, L2-hot; R3 showed
//     LDS staging of cands is neutral); addresses are wave-uniform.
//   blocks [256,261): fuse weights (5120 outputs = 5 x 1024):
//     WA = sA*(W2@L0) 32x64 @0    | WB = sB*(W1@L1) 64x32 @2048
//     WC = sC*(W4@L1) 16x32 @4096 | WD = sD*(W3@L2) 32x16 @4608
//     (non-transposed: msg's epilogue reads W[m*stride+u] coalesced across
//      lanes — R5's transposed/per-lane-row float4 variant was UNcoalesced,
//      the +20us regression.)
// ---------------------------------------------------------------------------
__global__ __launch_bounds__(1024, 4) void knn_all(
    const float* __restrict__ coords,
    const float* __restrict__ W1, const float* __restrict__ W2,
    const float* __restrict__ W3, const float* __restrict__ W4,
    const float* __restrict__ L0, const float* __restrict__ L1,
    const float* __restrict__ L2, float* __restrict__ Wf,
    int* __restrict__ nbr) {
  if (blockIdx.x >= 256) {             // -------- weight-fusion blocks
    const float sA = 0.012757759076995719f;  // sqrt(1/96)/8
    const float sB = 0.019764235376052370f;  // 1/sqrt(80*32)
    const float sC = 0.034232659844072875f;  // sqrt(3)/sqrt(80*32)
    const float sD = 0.098821176880261850f;  // sqrt(5/32)/4
    int idx = (blockIdx.x - 256) * 1024 + threadIdx.x;  // [0,5120)
    if (idx < 2048) {                       // WA: W2(32x64) @ L0(64x64)
      int u = idx >> 6, c = idx & 63;
      float a = 0.f;
#pragma unroll 8
      for (int m = 0; m < 64; m++) a += W2[u * 64 + m] * L0[m * 64 + c];
      Wf[idx] = sA * a;
    } else if (idx < 4096) {                // WB: W1(64x32) @ L1(32x32)
      int t = idx - 2048;
      int u = t >> 5, c = t & 31;
      float a = 0.f;
#pragma unroll 8
      for (int m = 0; m < 32; m++) a += W1[u * 32 + m] * L1[m * 32 + c];
      Wf[idx] = sB * a;
    } else if (idx < 4608) {                // WC: W4(16x32) @ L1(32x32)
      int t = idx - 4096;
      int u = t >> 5, c = t & 31;
      float a = 0.f;
#pragma unroll 8
      for (int m = 0; m < 32; m++) a += W4[u * 32 + m] * L1[m * 32 + c];
      Wf[idx] = sC * a;
    } else {                                // WD: W3(32x16) @ L2(16x16)
      int t = idx - 4608;
      int u = t >> 4, c = t & 15;
      float a = 0.f;
#pragma unroll 8
      for (int m = 0; m < 16; m++) a += W3[u * 16 + m] * L2[m * 16 + c];
      Wf[idx] = sD * a;
    }
    return;
  }

  // -------- fused kNN block
  __shared__ float pd[NSUB][QPB][KNBR + 1];   // 36.9 KB (stride 9: bank-ok)
  __shared__ int   pi[NSUB][QPB][KNBR + 1];   // 36.9 KB
  __shared__ float thrS[QPB];

  const int blk = blockIdx.x;
  const int b = blk >> 6;
  const int chunk = blk & 63;
  const int qi  = threadIdx.x & 63;           // query lane
  const int sub = threadIdx.x >> 6;           // 0..15
  const int iq  = chunk * 64 + qi;
  const float* cb = coords + (size_t)b * NN * 3;
  const float4* cb4 = (const float4*)cb;
  const float qx = cb[iq * 3 + 0], qy = cb[iq * 3 + 1], qz = cb[iq * 3 + 2];
  const int j0 = sub * 256;

  // ---- pass 1: top-2 distances over [j0, j0+256)
  float t0v = 3.0e38f, t1v = 3.0e38f;
#pragma unroll 4
  for (int g = 0; g < 64; ++g) {
    int base = j0 + 4 * g;                    // multiple of 4
    float4 f0 = cb4[3 * (base >> 2) + 0];     // wave-uniform addresses
    float4 f1 = cb4[3 * (base >> 2) + 1];
    float4 f2 = cb4[3 * (base >> 2) + 2];
    float xs[4] = {f0.x, f0.w, f1.z, f2.y};
    float ys[4] = {f0.y, f1.x, f1.w, f2.z};
    float zs[4] = {f0.z, f1.y, f2.x, f2.w};
#pragma unroll
    for (int c = 0; c < 4; ++c) {
      float dx = xs[c] - qx, dy = ys[c] - qy, dz = zs[c] - qz;
      float d2 = dx * dx + dy * dy + dz * dz;
      d2 = (base + c == iq) ? 3.0e38f : d2;   // exclude self
      t1v = __builtin_amdgcn_fmed3f(t0v, t1v, d2);
      t0v = fminf(t0v, d2);
    }
  }
  pd[sub][qi][0] = t0v;
  pd[sub][qi][1] = t1v;
  __syncthreads();

  // ---- threshold: 8th smallest of the 32 per-sub top-2 values
  if (threadIdx.x < 64) {
    const int q = threadIdx.x;
    float md[KNBR];
#pragma unroll
    for (int k = 0; k < KNBR; k++) md[k] = 3.0e38f;
    for (int s = 0; s < NSUB; s++) {
      insD(pd[s][q][0], md);
      insD(pd[s][q][1], md);
    }
    thrS[q] = md[KNBR - 1];
  }
  __syncthreads();

  // ---- pass 2: guarded exact collect
  const float tq = thrS[qi];
  float bd[KNBR];
  int bi[KNBR];
#pragma unroll
  for (int k = 0; k < KNBR; k++) { bd[k] = 3.0e38f; bi[k] = 0; }
#pragma unroll 2
  for (int g = 0; g < 64; ++g) {
    int base = j0 + 4 * g;
    float4 f0 = cb4[3 * (base >> 2) + 0];
    float4 f1 = cb4[3 * (base >> 2) + 1];
    float4 f2 = cb4[3 * (base >> 2) + 2];
    float xs[4] = {f0.x, f0.w, f1.z, f2.y};
    float ys[4] = {f0.y, f1.x, f1.w, f2.z};
    float zs[4] = {f0.z, f1.y, f2.x, f2.w};
#pragma unroll
    for (int c = 0; c < 4; ++c) {
      int jj = base + c;
      float dx = xs[c] - qx, dy = ys[c] - qy, dz = zs[c] - qz;
      float d2 = dx * dx + dy * dy + dz * dz;
      d2 = (jj == iq) ? 3.0e38f : d2;
      if (d2 <= tq) insertDI(d2, jj, bd, bi);   // rare path
    }
  }
#pragma unroll
  for (int k = 0; k < KNBR; k++) {
    pd[sub][qi][k] = bd[k];
    pi[sub][qi][k] = bi[k];
  }
  __syncthreads();

  // ---- final merge (ascending sub = ascending j) + write neighbor ids
  if (threadIdx.x < 64) {
    const int q = threadIdx.x;
    float md[KNBR];
    int mi[KNBR];
#pragma unroll
    for (int k = 0; k < KNBR; k++) { md[k] = 3.0e38f; mi[k] = 0; }
    for (int s = 0; s < NSUB; s++) {
#pragma unroll
      for (int k = 0; k < KNBR; k++) {
        float vd = pd[s][q][k];
        if (vd < md[KNBR - 1]) insertDI(vd, pi[s][q][k], md, mi);
      }
    }
    int* nr = nbr + (size_t)(b * NN + chunk * 64 + q) * KNBR;
#pragma unroll
    for (int k = 0; k < KNBR; k++) nr[k] = b * NN + mi[k];  // global node id
  }
}

// ---------------------------------------------------------------------------
// Kernel 2: gather + moments + fused weights + output.
// One wave per node; 4 nodes/block. (256,4): no spills (R2 lesson).
// XCD chunked swizzle (T1), bijective (4096 % 8 == 0).
// Epilogue: R4 coalesced form — W[m*stride+u] is contiguous ACROSS LANES
// per instruction (R5's per-lane-row float4 was the regression).
//
// Moments per node (432 floats in LDS):
//   S1[32] @0 | Z0[64][3] @32 | P[32][5] @224 | Q[16][3] @384
// ---------------------------------------------------------------------------
__global__ __launch_bounds__(256, 4) void msg_kernel(
    const float* __restrict__ feats, const float* __restrict__ coords,
    const int* __restrict__ nbr, const float* __restrict__ Wf,
    float* __restrict__ out) {
  __shared__ float accb[4][432];
  __shared__ float sev[4][KNBR][3];
  __shared__ int snb[4][KNBR];

  const int bid = ((blockIdx.x & 7) << 9) | (blockIdx.x >> 3);  // XCD chunks
  const int w = threadIdx.x >> 6;   // wave within block -> node slot
  const int u = threadIdx.x & 63;   // lane
  const int node = bid * 4 + w;

  if (u < KNBR) {
    int jg = nbr[(size_t)node * KNBR + u];
    snb[w][u] = jg;
    sev[w][u][0] = coords[(size_t)jg * 3 + 0] - coords[(size_t)node * 3 + 0];
    sev[w][u][1] = coords[(size_t)jg * 3 + 1] - coords[(size_t)node * 3 + 1];
    sev[w][u][2] = coords[(size_t)jg * 3 + 2] - coords[(size_t)node * 3 + 2];
  }
  __syncthreads();

  const float S_ = 0.31622776601683794f;  // 1/sqrt(10)
  const float T_ = 0.18257418583505536f;  // 1/sqrt(30)

  float z0x = 0.f, z0y = 0.f, z0z = 0.f;
  float s1 = 0.f, p0 = 0.f, p1 = 0.f, p2 = 0.f, p3 = 0.f, p4 = 0.f;
  float q0 = 0.f, q1 = 0.f, q2 = 0.f;

#pragma unroll
  for (int h = 0; h < 2; h++) {
    // ---- prefetch chunk of 4 neighbor rows into registers
    const float* fr[4];
    float xv[4], av0[4], av1[4], av2[4];
    float bv0[4], bv1[4], bv2[4], bv3[4], bv4[4];
#pragma unroll
    for (int i = 0; i < 4; i++) {
      fr[i] = feats + (size_t)snb[w][4 * h + i] * DF;
      xv[i] = fr[i][u];
    }
    if (u < 32) {
#pragma unroll
      for (int i = 0; i < 4; i++) {
        av0[i] = fr[i][64 + 3 * u];
        av1[i] = fr[i][65 + 3 * u];
        av2[i] = fr[i][66 + 3 * u];
      }
      if (u < 16) {
#pragma unroll
        for (int i = 0; i < 4; i++) {
          bv0[i] = fr[i][160 + 5 * u];
          bv1[i] = fr[i][161 + 5 * u];
          bv2[i] = fr[i][162 + 5 * u];
          bv3[i] = fr[i][163 + 5 * u];
          bv4[i] = fr[i][164 + 5 * u];
        }
      }
    }
    // ---- consume chunk
#pragma unroll
    for (int i = 0; i < 4; i++) {
      const int e = 4 * h + i;
      float X = sev[w][e][0], Y = sev[w][e][1], Z = sev[w][e][2];
      float sxv = S_ * X, syv = S_ * Y, szv = S_ * Z;
      float txv = T_ * X, tyv = T_ * Y, t2z = 2.f * T_ * Z;
      z0x += xv[i] * X;
      z0y += xv[i] * Y;
      z0z += xv[i] * Z;
      if (u < 32) {
        s1 += av0[i] * X + av1[i] * Y + av2[i] * Z;
        p0 += av0[i] * syv + av1[i] * sxv;
        p1 += av0[i] * szv + av2[i] * sxv;
        p2 += av1[i] * szv + av2[i] * syv;
        p3 += av0[i] * sxv - av1[i] * syv;
        p4 += av2[i] * t2z - av0[i] * txv - av1[i] * tyv;
        if (u < 16) {
          q0 += bv0[i] * syv + bv1[i] * szv + bv3[i] * sxv - bv4[i] * txv;
          q1 += bv0[i] * sxv + bv2[i] * szv - bv3[i] * syv - bv4[i] * tyv;
          q2 += bv1[i] * sxv + bv2[i] * syv + bv4[i] * t2z;
        }
      }
    }
  }

  float* A = accb[w];
  A[32 + 3 * u + 0] = z0x;
  A[32 + 3 * u + 1] = z0y;
  A[32 + 3 * u + 2] = z0z;
  if (u < 32) {
    A[u] = s1;
    float* pp = A + 224 + 5 * u;
    pp[0] = p0; pp[1] = p1; pp[2] = p2; pp[3] = p3; pp[4] = p4;
  }
  if (u < 16) {
    float* qq = A + 384 + 3 * u;
    qq[0] = q0; qq[1] = q1; qq[2] = q2;
  }
  __syncthreads();

  const float* WA = Wf;          // 32x64
  const float* WB = Wf + 2048;   // 64x32
  const float* WC = Wf + 4096;   // 16x32
  const float* WD = Wf + 4608;   // 32x16
  float* orow = out + (size_t)node * DF;

  // y0[u] = sum_m S1[m] * WA[m][u]   (coalesced across lanes)
  {
    float a = 0.f;
#pragma unroll
    for (int m = 0; m < 32; m++) a += A[m] * WA[m * 64 + u];
    orow[u] = a;
  }
  // y1 flat [w1*3+k], 96 outputs (two passes over 64 lanes)
#pragma unroll
  for (int m0 = 0; m0 < 96; m0 += 64) {
    int m = m0 + u;
    if (m < 96) {
      int w1 = m / 3, k = m - w1 * 3;
      float a = 0.f;
#pragma unroll
      for (int t = 0; t < 64; t++) a += A[32 + 3 * t + k] * WB[t * 32 + w1];
#pragma unroll
      for (int t = 0; t < 16; t++) a += A[384 + 3 * t + k] * WC[t * 32 + w1];
      orow[64 + m] = a;
    }
  }
  // y2 flat [w2*5+k], 80 outputs (two passes over 64 lanes)
#pragma unroll
  for (int m0 = 0; m0 < 80; m0 += 64) {
    int m = m0 + u;
    if (m < 80) {
      int w2 = m / 5, k = m - w2 * 5;
      float a = 0.f;
#pragma unroll
      for (int t = 0; t < 32; t++) a += A[224 + 5 * t + k] * WD[t * 16 + w2];
      orow[160 + m] = a;
    }
  }
}

// ---------------------------------------------------------------------------
extern "C" void kernel_launch(void* const* d_in, const int* in_sizes, int n_in,
                              void* d_out, int out_size, void* d_ws,
                              size_t ws_size, hipStream_t stream) {
  const float* feats  = (const float*)d_in[0];
  const float* coords = (const float*)d_in[1];
  const float* W1 = (const float*)d_in[2];
  const float* W2 = (const float*)d_in[3];
  const float* W3 = (const float*)d_in[4];
  const float* W4 = (const float*)d_in[5];
  const float* L0 = (const float*)d_in[6];
  const float* L1 = (const float*)d_in[7];
  const float* L2 = (const float*)d_in[8];
  float* out = (float*)d_out;

  // workspace (floats): Wf[5120] | nbr[131072 ints]  -> ~0.55 MB
  float* Wf  = (float*)d_ws;
  int*   nbr = (int*)((float*)d_ws + 5120);

  knn_all<<<261, 1024, 0, stream>>>(coords, W1, W2, W3, W4, L0, L1, L2, Wf,
                                    nbr);
  msg_kernel<<<4096, 256, 0, stream>>>(feats, coords, nbr, Wf, out);
}

// Round 7
// 190.240 us; speedup vs baseline: 1.1177x; 1.0305x over previous
//
#include <hip/hip_runtime.h>

#define NN   4096
#define KNBR 8
#define DF   240
#define NSUB 16   // candidate sub-ranges (waves) per kNN block
#define QPB  64   // queries per kNN block

// Distance-only sorted-top-8 insert: pure med3/min chain.
__device__ __forceinline__ void insD(float v, float t[KNBR]) {
#pragma unroll
  for (int k = KNBR - 1; k >= 1; k--)
    t[k] = __builtin_amdgcn_fmed3f(t[k - 1], t[k], v);
  t[0] = fminf(t[0], v);
}

// (distance,index) sorted-top-8 insert — proven formulation:
__device__ __forceinline__ void insertDI(float d2, int j, float bd[KNBR],
                                         int bi[KNBR]) {
#pragma unroll
  for (int k = KNBR - 1; k >= 1; k--) {
    bool mk  = d2 < bd[k];
    bool mk1 = d2 < bd[k - 1];
    bd[k] = mk ? (mk1 ? bd[k - 1] : d2) : bd[k];
    bi[k] = mk ? (mk1 ? bi[k - 1] : j) : bi[k];
  }
  bool m0 = d2 < bd[0];
  bd[0] = m0 ? d2 : bd[0];
  bi[0] = m0 ? j : bi[0];
}

// ---------------------------------------------------------------------------
// Kernel 1: the ENTIRE kNN in one kernel ⊕ weight fusion.
//   blocks [0,256): block = (batch, 64-query chunk). 16 waves, each owning a
//     256-candidate sub-range; lane = query.
//     R7: ALL 4096 candidate coords staged to LDS once (raw float4 image,
//     48 KB, 3 float4/thread coalesced). Both passes read wave-uniform LDS
//     (broadcast, conflict-free) — removes the exposed ~250cy L2 latency
//     that R6 counters showed (VALUBusy 58%, 1 block/CU, no TLP to hide it).
//       pass 1: per-sub top-2 distances -> LDS  (2 VALU/cand insert)
//       thr:    8th smallest of the 32 top-2 values (threads<64). Valid:
//               any SUBSET's 8th-smallest >= true 8th -> collect admits a
//               superset; collect stays exact.
//       pass 2: group-guard (min-of-4 vs thr) then exact insertDI ->
//               per-sub top-8 (pi stored as ushort: j < 4096)
//       merge:  ascending sub = ascending j, strict-< insertion ==
//               reference stable top_k tie-break. Sentinels (3e38) never
//               insert. Writes final 8 GLOBAL neighbor ids.
//     LDS: 48K cand + 36.9K pd + 18.4K pi(ushort) + thrS ~= 103.6 KB.
//   blocks [256,261): fuse weights (5120 outputs = 5 x 1024):
//     WA = sA*(W2@L0) 32x64 @0    | WB = sB*(W1@L1) 64x32 @2048
//     WC = sC*(W4@L1) 16x32 @4096 | WD = sD*(W3@L2) 32x16 @4608
//     (non-transposed: msg's epilogue reads W[m*stride+u] coalesced across
//      lanes — R5's transposed variant was the uncoalesced regression.)
// ---------------------------------------------------------------------------
__global__ __launch_bounds__(1024, 4) void knn_all(
    const float* __restrict__ coords,
    const float* __restrict__ W1, const float* __restrict__ W2,
    const float* __restrict__ W3, const float* __restrict__ W4,
    const float* __restrict__ L0, const float* __restrict__ L1,
    const float* __restrict__ L2, float* __restrict__ Wf,
    int* __restrict__ nbr) {
  if (blockIdx.x >= 256) {             // -------- weight-fusion blocks
    const float sA = 0.012757759076995719f;  // sqrt(1/96)/8
    const float sB = 0.019764235376052370f;  // 1/sqrt(80*32)
    const float sC = 0.034232659844072875f;  // sqrt(3)/sqrt(80*32)
    const float sD = 0.098821176880261850f;  // sqrt(5/32)/4
    int idx = (blockIdx.x - 256) * 1024 + threadIdx.x;  // [0,5120)
    if (idx < 2048) {                       // WA: W2(32x64) @ L0(64x64)
      int u = idx >> 6, c = idx & 63;
      float a = 0.f;
#pragma unroll 8
      for (int m = 0; m < 64; m++) a += W2[u * 64 + m] * L0[m * 64 + c];
      Wf[idx] = sA * a;
    } else if (idx < 4096) {                // WB: W1(64x32) @ L1(32x32)
      int t = idx - 2048;
      int u = t >> 5, c = t & 31;
      float a = 0.f;
#pragma unroll 8
      for (int m = 0; m < 32; m++) a += W1[u * 32 + m] * L1[m * 32 + c];
      Wf[idx] = sB * a;
    } else if (idx < 4608) {                // WC: W4(16x32) @ L1(32x32)
      int t = idx - 4096;
      int u = t >> 5, c = t & 31;
      float a = 0.f;
#pragma unroll 8
      for (int m = 0; m < 32; m++) a += W4[u * 32 + m] * L1[m * 32 + c];
      Wf[idx] = sC * a;
    } else {                                // WD: W3(32x16) @ L2(16x16)
      int t = idx - 4608;
      int u = t >> 4, c = t & 15;
      float a = 0.f;
#pragma unroll 8
      for (int m = 0; m < 16; m++) a += W3[u * 16 + m] * L2[m * 16 + c];
      Wf[idx] = sD * a;
    }
    return;
  }

  // -------- fused kNN block
  __shared__ float4 cnd[3072];                        // 48 KB raw coord image
  __shared__ float pd[NSUB][QPB][KNBR + 1];           // 36.9 KB
  __shared__ unsigned short pi[NSUB][QPB][KNBR + 1];  // 18.4 KB
  __shared__ float thrS[QPB];

  const int blk = blockIdx.x;
  const int b = blk >> 6;
  const int chunk = blk & 63;
  const int qi  = threadIdx.x & 63;           // query lane
  const int sub = threadIdx.x >> 6;           // 0..15
  const int iq  = chunk * 64 + qi;
  const float* cb = coords + (size_t)b * NN * 3;
  const float4* cb4 = (const float4*)cb;

  {  // stage all 4096 candidates: 3072 float4, 3 per thread, coalesced
    int t = threadIdx.x;
    cnd[t]        = cb4[t];
    cnd[1024 + t] = cb4[1024 + t];
    cnd[2048 + t] = cb4[2048 + t];
  }
  const float qx = cb[iq * 3 + 0], qy = cb[iq * 3 + 1], qz = cb[iq * 3 + 2];
  __syncthreads();

  const int j0 = sub * 256;

  // ---- pass 1: top-2 distances over [j0, j0+256), candidates from LDS
  float t0v = 3.0e38f, t1v = 3.0e38f;
#pragma unroll 4
  for (int g = 0; g < 64; ++g) {
    int base = j0 + 4 * g;                    // multiple of 4
    int f = 3 * (sub * 64 + g);               // float4 index of this group
    float4 f0 = cnd[f + 0];                   // wave-uniform -> broadcast
    float4 f1 = cnd[f + 1];
    float4 f2 = cnd[f + 2];
    float xs[4] = {f0.x, f0.w, f1.z, f2.y};
    float ys[4] = {f0.y, f1.x, f1.w, f2.z};
    float zs[4] = {f0.z, f1.y, f2.x, f2.w};
#pragma unroll
    for (int c = 0; c < 4; ++c) {
      float dx = xs[c] - qx, dy = ys[c] - qy, dz = zs[c] - qz;
      float d2 = dx * dx + dy * dy + dz * dz;
      d2 = (base + c == iq) ? 3.0e38f : d2;   // exclude self
      t1v = __builtin_amdgcn_fmed3f(t0v, t1v, d2);
      t0v = fminf(t0v, d2);
    }
  }
  pd[sub][qi][0] = t0v;
  pd[sub][qi][1] = t1v;
  __syncthreads();

  // ---- threshold: 8th smallest of the 32 per-sub top-2 values
  if (threadIdx.x < 64) {
    const int q = threadIdx.x;
    float md[KNBR];
#pragma unroll
    for (int k = 0; k < KNBR; k++) md[k] = 3.0e38f;
    for (int s = 0; s < NSUB; s++) {
      insD(pd[s][q][0], md);
      insD(pd[s][q][1], md);
    }
    thrS[q] = md[KNBR - 1];
  }
  __syncthreads();

  // ---- pass 2: group-guarded exact collect (candidates from LDS)
  const float tq = thrS[qi];
  float bd[KNBR];
  int bi[KNBR];
#pragma unroll
  for (int k = 0; k < KNBR; k++) { bd[k] = 3.0e38f; bi[k] = 0; }
#pragma unroll 2
  for (int g = 0; g < 64; ++g) {
    int base = j0 + 4 * g;
    int f = 3 * (sub * 64 + g);
    float4 f0 = cnd[f + 0];
    float4 f1 = cnd[f + 1];
    float4 f2 = cnd[f + 2];
    float xs[4] = {f0.x, f0.w, f1.z, f2.y};
    float ys[4] = {f0.y, f1.x, f1.w, f2.z};
    float zs[4] = {f0.z, f1.y, f2.x, f2.w};
    float d2s[4];
#pragma unroll
    for (int c = 0; c < 4; ++c) {
      float dx = xs[c] - qx, dy = ys[c] - qy, dz = zs[c] - qz;
      float d2 = dx * dx + dy * dy + dz * dz;
      d2s[c] = (base + c == iq) ? 3.0e38f : d2;
    }
    float m4 = fminf(fminf(d2s[0], d2s[1]), fminf(d2s[2], d2s[3]));
    if (m4 <= tq) {                           // group guard: rare
#pragma unroll
      for (int c = 0; c < 4; ++c)
        if (d2s[c] <= tq) insertDI(d2s[c], base + c, bd, bi);
    }
  }
#pragma unroll
  for (int k = 0; k < KNBR; k++) {
    pd[sub][qi][k] = bd[k];
    pi[sub][qi][k] = (unsigned short)bi[k];
  }
  __syncthreads();

  // ---- final merge (ascending sub = ascending j) + write neighbor ids
  if (threadIdx.x < 64) {
    const int q = threadIdx.x;
    float md[KNBR];
    int mi[KNBR];
#pragma unroll
    for (int k = 0; k < KNBR; k++) { md[k] = 3.0e38f; mi[k] = 0; }
    for (int s = 0; s < NSUB; s++) {
#pragma unroll
      for (int k = 0; k < KNBR; k++) {
        float vd = pd[s][q][k];
        if (vd < md[KNBR - 1]) insertDI(vd, (int)pi[s][q][k], md, mi);
      }
    }
    int* nr = nbr + (size_t)(b * NN + chunk * 64 + q) * KNBR;
#pragma unroll
    for (int k = 0; k < KNBR; k++) nr[k] = b * NN + mi[k];  // global node id
  }
}

// ---------------------------------------------------------------------------
// Kernel 2: gather + moments + fused weights + output.
// One wave per node; 4 nodes/block. (256,4): no spills (R2 lesson).
// XCD chunked swizzle (T1), bijective (4096 % 8 == 0).
// Epilogue: coalesced form — W[m*stride+u] contiguous ACROSS LANES
// (R5's per-lane-row float4 was the regression).
//
// Moments per node (432 floats in LDS):
//   S1[32] @0 | Z0[64][3] @32 | P[32][5] @224 | Q[16][3] @384
// ---------------------------------------------------------------------------
__global__ __launch_bounds__(256, 4) void msg_kernel(
    const float* __restrict__ feats, const float* __restrict__ coords,
    const int* __restrict__ nbr, const float* __restrict__ Wf,
    float* __restrict__ out) {
  __shared__ float accb[4][432];
  __shared__ float sev[4][KNBR][3];
  __shared__ int snb[4][KNBR];

  const int bid = ((blockIdx.x & 7) << 9) | (blockIdx.x >> 3);  // XCD chunks
  const int w = threadIdx.x >> 6;   // wave within block -> node slot
  const int u = threadIdx.x & 63;   // lane
  const int node = bid * 4 + w;

  if (u < KNBR) {
    int jg = nbr[(size_t)node * KNBR + u];
    snb[w][u] = jg;
    sev[w][u][0] = coords[(size_t)jg * 3 + 0] - coords[(size_t)node * 3 + 0];
    sev[w][u][1] = coords[(size_t)jg * 3 + 1] - coords[(size_t)node * 3 + 1];
    sev[w][u][2] = coords[(size_t)jg * 3 + 2] - coords[(size_t)node * 3 + 2];
  }
  __syncthreads();

  const float S_ = 0.31622776601683794f;  // 1/sqrt(10)
  const float T_ = 0.18257418583505536f;  // 1/sqrt(30)

  float z0x = 0.f, z0y = 0.f, z0z = 0.f;
  float s1 = 0.f, p0 = 0.f, p1 = 0.f, p2 = 0.f, p3 = 0.f, p4 = 0.f;
  float q0 = 0.f, q1 = 0.f, q2 = 0.f;

#pragma unroll
  for (int h = 0; h < 2; h++) {
    // ---- prefetch chunk of 4 neighbor rows into registers
    const float* fr[4];
    float xv[4], av0[4], av1[4], av2[4];
    float bv0[4], bv1[4], bv2[4], bv3[4], bv4[4];
#pragma unroll
    for (int i = 0; i < 4; i++) {
      fr[i] = feats + (size_t)snb[w][4 * h + i] * DF;
      xv[i] = fr[i][u];
    }
    if (u < 32) {
#pragma unroll
      for (int i = 0; i < 4; i++) {
        av0[i] = fr[i][64 + 3 * u];
        av1[i] = fr[i][65 + 3 * u];
        av2[i] = fr[i][66 + 3 * u];
      }
      if (u < 16) {
#pragma unroll
        for (int i = 0; i < 4; i++) {
          bv0[i] = fr[i][160 + 5 * u];
          bv1[i] = fr[i][161 + 5 * u];
          bv2[i] = fr[i][162 + 5 * u];
          bv3[i] = fr[i][163 + 5 * u];
          bv4[i] = fr[i][164 + 5 * u];
        }
      }
    }
    // ---- consume chunk
#pragma unroll
    for (int i = 0; i < 4; i++) {
      const int e = 4 * h + i;
      float X = sev[w][e][0], Y = sev[w][e][1], Z = sev[w][e][2];
      float sxv = S_ * X, syv = S_ * Y, szv = S_ * Z;
      float txv = T_ * X, tyv = T_ * Y, t2z = 2.f * T_ * Z;
      z0x += xv[i] * X;
      z0y += xv[i] * Y;
      z0z += xv[i] * Z;
      if (u < 32) {
        s1 += av0[i] * X + av1[i] * Y + av2[i] * Z;
        p0 += av0[i] * syv + av1[i] * sxv;
        p1 += av0[i] * szv + av2[i] * sxv;
        p2 += av1[i] * szv + av2[i] * syv;
        p3 += av0[i] * sxv - av1[i] * syv;
        p4 += av2[i] * t2z - av0[i] * txv - av1[i] * tyv;
        if (u < 16) {
          q0 += bv0[i] * syv + bv1[i] * szv + bv3[i] * sxv - bv4[i] * txv;
          q1 += bv0[i] * sxv + bv2[i] * szv - bv3[i] * syv - bv4[i] * tyv;
          q2 += bv1[i] * sxv + bv2[i] * syv + bv4[i] * t2z;
        }
      }
    }
  }

  float* A = accb[w];
  A[32 + 3 * u + 0] = z0x;
  A[32 + 3 * u + 1] = z0y;
  A[32 + 3 * u + 2] = z0z;
  if (u < 32) {
    A[u] = s1;
    float* pp = A + 224 + 5 * u;
    pp[0] = p0; pp[1] = p1; pp[2] = p2; pp[3] = p3; pp[4] = p4;
  }
  if (u < 16) {
    float* qq = A + 384 + 3 * u;
    qq[0] = q0; qq[1] = q1; qq[2] = q2;
  }
  __syncthreads();

  const float* WA = Wf;          // 32x64
  const float* WB = Wf + 2048;   // 64x32
  const float* WC = Wf + 4096;   // 16x32
  const float* WD = Wf + 4608;   // 32x16
  float* orow = out + (size_t)node * DF;

  // y0[u] = sum_m S1[m] * WA[m][u]   (coalesced across lanes)
  {
    float a = 0.f;
#pragma unroll
    for (int m = 0; m < 32; m++) a += A[m] * WA[m * 64 + u];
    orow[u] = a;
  }
  // y1 flat [w1*3+k], 96 outputs (two passes over 64 lanes)
#pragma unroll
  for (int m0 = 0; m0 < 96; m0 += 64) {
    int m = m0 + u;
    if (m < 96) {
      int w1 = m / 3, k = m - w1 * 3;
      float a = 0.f;
#pragma unroll
      for (int t = 0; t < 64; t++) a += A[32 + 3 * t + k] * WB[t * 32 + w1];
#pragma unroll
      for (int t = 0; t < 16; t++) a += A[384 + 3 * t + k] * WC[t * 32 + w1];
      orow[64 + m] = a;
    }
  }
  // y2 flat [w2*5+k], 80 outputs (two passes over 64 lanes)
#pragma unroll
  for (int m0 = 0; m0 < 80; m0 += 64) {
    int m = m0 + u;
    if (m < 80) {
      int w2 = m / 5, k = m - w2 * 5;
      float a = 0.f;
#pragma unroll
      for (int t = 0; t < 32; t++) a += A[224 + 5 * t + k] * WD[t * 16 + w2];
      orow[160 + m] = a;
    }
  }
}

// ---------------------------------------------------------------------------
extern "C" void kernel_launch(void* const* d_in, const int* in_sizes, int n_in,
                              void* d_out, int out_size, void* d_ws,
                              size_t ws_size, hipStream_t stream) {
  const float* feats  = (const float*)d_in[0];
  const float* coords = (const float*)d_in[1];
  const float* W1 = (const float*)d_in[2];
  const float* W2 = (const float*)d_in[3];
  const float* W3 = (const float*)d_in[4];
  const float* W4 = (const float*)d_in[5];
  const float* L0 = (const float*)d_in[6];
  const float* L1 = (const float*)d_in[7];
  const float* L2 = (const float*)d_in[8];
  float* out = (float*)d_out;

  // workspace (floats): Wf[5120] | nbr[131072 ints]  -> ~0.55 MB
  float* Wf  = (float*)d_ws;
  int*   nbr = (int*)((float*)d_ws + 5120);

  knn_all<<<261, 1024, 0, stream>>>(coords, W1, W2, W3, W4, L0, L1, L2, Wf,
                                    nbr);
  msg_kernel<<<4096, 256, 0, stream>>>(feats, coords, nbr, Wf, out);
}

// Round 8
// 190.212 us; speedup vs baseline: 1.1178x; 1.0001x over previous
//
#include <hip/hip_runtime.h>

#define NN   4096
#define KNBR 8
#define DF   240
#define NSUB 16   // candidate sub-ranges (waves) per kNN block
#define QPB  64   // queries per kNN block

// LDS layout (bytes). Phase A (kNN): cnd/pd/pi/thr/nbrL. Phase B (msg):
// WfL/sevL/snbL/accL — all dead-alias phase-A regions except nbrL.
#define OFF_PD   49152   // float [16][64][9]  = 36864
#define OFF_PI   86016   // ushort[16][64][9]  = 18432
#define OFF_THR  104448  // float [64]         = 256
#define OFF_NBR  104704  // int   [64][8]      = 2048 (merge -> stage handoff)
#define OFF_WF   0       // float [5120]       = 20480
#define OFF_SEV  20480   // float [64][8][3]   = 6144
#define OFF_SNB  26624   // int   [64][8]      = 2048
#define OFF_ACC  28672   // float [16][432]    = 27648
#define SMEM_SZ  106752

// 9-deep distance-only sorted insert (for the 9th-smallest threshold).
__device__ __forceinline__ void insD9(float v, float t[9]) {
#pragma unroll
  for (int k = 8; k >= 1; k--)
    t[k] = __builtin_amdgcn_fmed3f(t[k - 1], t[k], v);
  t[0] = fminf(t[0], v);
}

// (distance,index) sorted-top-8 insert — proven formulation:
__device__ __forceinline__ void insertDI(float d2, int j, float bd[KNBR],
                                         int bi[KNBR]) {
#pragma unroll
  for (int k = KNBR - 1; k >= 1; k--) {
    bool mk  = d2 < bd[k];
    bool mk1 = d2 < bd[k - 1];
    bd[k] = mk ? (mk1 ? bd[k - 1] : d2) : bd[k];
    bi[k] = mk ? (mk1 ? bi[k - 1] : j) : bi[k];
  }
  bool m0 = d2 < bd[0];
  bd[0] = m0 ? d2 : bd[0];
  bi[0] = m0 ? j : bi[0];
}

// ---------------------------------------------------------------------------
// ONE kernel, grid 256 x 1024. Block blk (b=blk>>6, chunk=blk&63) owns the 64
// nodes [blk*64, blk*64+64): it computes their kNN AND their messages — the
// producer and consumer are the same block, so no second launch, no global
// nbr, no global Wf, no grid sync. R7 post-mortem: knn 68 + msg <=68 inside a
// 190 us wall -> ~55 us inter-kernel overhead was the biggest cost item.
//
// Phase A (kNN, verified structure from R7):
//   A1: stage all 4096 cands to LDS (raw float4 image, coalesced).
//   A2: per-sub top-2 distances. R8: self-mask REMOVED from this loop
//       (10->8 VALU/cand); threshold compensates (below).
//   A3: thr = 9TH smallest of the 32 values. The self-distance 0 is present
//       exactly once and is the minimum, so 9th-of-(S u {0}) = 8th-of-S,
//       a subset of real distances -> thr >= true 8th. Exact.
//   A4: guarded collect (keeps self mask; group min-of-4 guard).
//   A5: merge (ascending sub = ascending j, strict-< == reference stable
//       tie-break) -> nbrL in LDS (batch-local ids). No global round-trip.
//
// Phase B (msg):
//   B1: weight fusion computed REDUNDANTLY per block into LDS (~230k FMA
//       across 1024 thr = ~0.4 us) + sev/snb staging from nbrL.
//   B2: per wave: 4 nodes sequentially — gather-moments (R4 prefetch form),
//       epilogue from LDS weights. No block barriers inside: each wave owns
//       its accL slice; same-wave LDS RAW ordered by explicit lgkmcnt(0)
//       fences ("memory" clobber orders ds ops; rule-18 hoisting concerns
//       register-only consumers). Waves free-run -> VMEM/DS overlap.
// ---------------------------------------------------------------------------
__global__ __launch_bounds__(1024, 4) void fused_all(
    const float* __restrict__ feats, const float* __restrict__ coords,
    const float* __restrict__ W1, const float* __restrict__ W2,
    const float* __restrict__ W3, const float* __restrict__ W4,
    const float* __restrict__ L0, const float* __restrict__ L1,
    const float* __restrict__ L2, float* __restrict__ out) {
  __shared__ __align__(16) char smem[SMEM_SZ];

  const int blk = blockIdx.x;
  const int b = blk >> 6;
  const int chunk = blk & 63;
  const int qi  = threadIdx.x & 63;           // query lane
  const int sub = threadIdx.x >> 6;           // 0..15
  const int iq  = chunk * 64 + qi;
  const float* cb = coords + (size_t)b * NN * 3;
  const float4* cb4 = (const float4*)cb;

  float4* cnd = (float4*)smem;
  float* pdB = (float*)(smem + OFF_PD);            // (s*64+q)*9 + k
  unsigned short* piB = (unsigned short*)(smem + OFF_PI);
  float* thrS = (float*)(smem + OFF_THR);
  int* nbrL = (int*)(smem + OFF_NBR);

  {  // A1: stage all 4096 candidates: 3072 float4, 3 per thread, coalesced
    int t = threadIdx.x;
    cnd[t]        = cb4[t];
    cnd[1024 + t] = cb4[1024 + t];
    cnd[2048 + t] = cb4[2048 + t];
  }
  const float qx = cb[iq * 3 + 0], qy = cb[iq * 3 + 1], qz = cb[iq * 3 + 2];
  __syncthreads();

  const int j0 = sub * 256;

  // ---- A2: top-2 distances over [j0, j0+256) (no self mask; see A3)
  float t0v = 3.0e38f, t1v = 3.0e38f;
#pragma unroll 4
  for (int g = 0; g < 64; ++g) {
    int f = 3 * (sub * 64 + g);
    float4 f0 = cnd[f + 0];                   // wave-uniform -> broadcast
    float4 f1 = cnd[f + 1];
    float4 f2 = cnd[f + 2];
    float xs[4] = {f0.x, f0.w, f1.z, f2.y};
    float ys[4] = {f0.y, f1.x, f1.w, f2.z};
    float zs[4] = {f0.z, f1.y, f2.x, f2.w};
#pragma unroll
    for (int c = 0; c < 4; ++c) {
      float dx = xs[c] - qx, dy = ys[c] - qy, dz = zs[c] - qz;
      float d2 = dx * dx + dy * dy + dz * dz;
      t1v = __builtin_amdgcn_fmed3f(t0v, t1v, d2);
      t0v = fminf(t0v, d2);
    }
  }
  pdB[(sub * 64 + qi) * 9 + 0] = t0v;
  pdB[(sub * 64 + qi) * 9 + 1] = t1v;
  __syncthreads();

  // ---- A3: thr = 9th smallest of 32 values (self-0 present exactly once)
  if (threadIdx.x < 64) {
    const int q = threadIdx.x;
    float md[9];
#pragma unroll
    for (int k = 0; k < 9; k++) md[k] = 3.0e38f;
    for (int s = 0; s < NSUB; s++) {
      insD9(pdB[(s * 64 + q) * 9 + 0], md);
      insD9(pdB[(s * 64 + q) * 9 + 1], md);
    }
    thrS[q] = md[8];
  }
  __syncthreads();

  // ---- A4: group-guarded exact collect (self masked here)
  const float tq = thrS[qi];
  float bd[KNBR];
  int bi[KNBR];
#pragma unroll
  for (int k = 0; k < KNBR; k++) { bd[k] = 3.0e38f; bi[k] = 0; }
#pragma unroll 2
  for (int g = 0; g < 64; ++g) {
    int base = j0 + 4 * g;
    int f = 3 * (sub * 64 + g);
    float4 f0 = cnd[f + 0];
    float4 f1 = cnd[f + 1];
    float4 f2 = cnd[f + 2];
    float xs[4] = {f0.x, f0.w, f1.z, f2.y};
    float ys[4] = {f0.y, f1.x, f1.w, f2.z};
    float zs[4] = {f0.z, f1.y, f2.x, f2.w};
    float d2s[4];
#pragma unroll
    for (int c = 0; c < 4; ++c) {
      float dx = xs[c] - qx, dy = ys[c] - qy, dz = zs[c] - qz;
      float d2 = dx * dx + dy * dy + dz * dz;
      d2s[c] = (base + c == iq) ? 3.0e38f : d2;
    }
    float m4 = fminf(fminf(d2s[0], d2s[1]), fminf(d2s[2], d2s[3]));
    if (m4 <= tq) {                           // rare
#pragma unroll
      for (int c = 0; c < 4; ++c)
        if (d2s[c] <= tq) insertDI(d2s[c], base + c, bd, bi);
    }
  }
#pragma unroll
  for (int k = 0; k < KNBR; k++) {
    pdB[(sub * 64 + qi) * 9 + k] = bd[k];
    piB[(sub * 64 + qi) * 9 + k] = (unsigned short)bi[k];
  }
  __syncthreads();

  // ---- A5: final merge -> nbrL (batch-local ids), LDS only
  if (threadIdx.x < 64) {
    const int q = threadIdx.x;
    float md[KNBR];
    int mi[KNBR];
#pragma unroll
    for (int k = 0; k < KNBR; k++) { md[k] = 3.0e38f; mi[k] = 0; }
    for (int s = 0; s < NSUB; s++) {
#pragma unroll
      for (int k = 0; k < KNBR; k++) {
        float vd = pdB[(s * 64 + q) * 9 + k];
        if (vd < md[KNBR - 1]) insertDI(vd, (int)piB[(s * 64 + q) * 9 + k],
                                        md, mi);
      }
    }
#pragma unroll
    for (int k = 0; k < KNBR; k++) nbrL[q * KNBR + k] = mi[k];
  }
  __syncthreads();

  // ================= Phase B =================
  float* WfL  = (float*)(smem + OFF_WF);
  float* sevL = (float*)(smem + OFF_SEV);
  int*   snbL = (int*)(smem + OFF_SNB);
  float* accL = (float*)(smem + OFF_ACC);

  // ---- B1a: per-block weight fusion into LDS (5 entries per thread)
  {
    const float sA = 0.012757759076995719f;  // sqrt(1/96)/8
    const float sB = 0.019764235376052370f;  // 1/sqrt(80*32)
    const float sC = 0.034232659844072875f;  // sqrt(3)/sqrt(80*32)
    const float sD = 0.098821176880261850f;  // sqrt(5/32)/4
#pragma unroll
    for (int i = 0; i < 5; i++) {
      int idx = threadIdx.x + 1024 * i;      // [0,5120)
      if (idx < 2048) {                      // WA: W2(32x64) @ L0(64x64)
        int u2 = idx >> 6, c = idx & 63;
        float a = 0.f;
#pragma unroll 8
        for (int m = 0; m < 64; m++) a += W2[u2 * 64 + m] * L0[m * 64 + c];
        WfL[idx] = sA * a;
      } else if (idx < 4096) {               // WB: W1(64x32) @ L1(32x32)
        int t = idx - 2048;
        int u2 = t >> 5, c = t & 31;
        float a = 0.f;
#pragma unroll 8
        for (int m = 0; m < 32; m++) a += W1[u2 * 32 + m] * L1[m * 32 + c];
        WfL[idx] = sB * a;
      } else if (idx < 4608) {               // WC: W4(16x32) @ L1(32x32)
        int t = idx - 4096;
        int u2 = t >> 5, c = t & 31;
        float a = 0.f;
#pragma unroll 8
        for (int m = 0; m < 32; m++) a += W4[u2 * 32 + m] * L1[m * 32 + c];
        WfL[idx] = sC * a;
      } else {                               // WD: W3(32x16) @ L2(16x16)
        int t = idx - 4608;
        int u2 = t >> 4, c = t & 15;
        float a = 0.f;
#pragma unroll 8
        for (int m = 0; m < 16; m++) a += W3[u2 * 16 + m] * L2[m * 16 + c];
        WfL[idx] = sD * a;
      }
    }
  }
  // ---- B1b: sev/snb staging (64 nodes x 8 nbrs, coords from global/L2)
  if (threadIdx.x < 512) {
    int t = threadIdx.x;
    int nl = t >> 3, e = t & 7;
    int jj = nbrL[nl * KNBR + e];            // batch-local
    int iqn = chunk * 64 + nl;
    snbL[t] = b * NN + jj;                   // global id for feats
    sevL[3 * t + 0] = cb[jj * 3 + 0] - cb[iqn * 3 + 0];
    sevL[3 * t + 1] = cb[jj * 3 + 1] - cb[iqn * 3 + 1];
    sevL[3 * t + 2] = cb[jj * 3 + 2] - cb[iqn * 3 + 2];
  }
  __syncthreads();

  // ---- B2: per wave, 4 nodes sequentially (no block barriers)
  const float S_ = 0.31622776601683794f;  // 1/sqrt(10)
  const float T_ = 0.18257418583505536f;  // 1/sqrt(30)
  const int w = threadIdx.x >> 6;
  const int u = threadIdx.x & 63;
  float* A = accL + w * 432;   // S1[32]@0 | Z0[64][3]@32 | P[32][5]@224 | Q[16][3]@384

  for (int i2 = 0; i2 < 4; i2++) {
    const int nl = w * 4 + i2;
    const int node = blk * 64 + nl;          // global node id

    float z0x = 0.f, z0y = 0.f, z0z = 0.f;
    float s1 = 0.f, p0 = 0.f, p1 = 0.f, p2 = 0.f, p3 = 0.f, p4 = 0.f;
    float q0 = 0.f, q1 = 0.f, q2 = 0.f;

#pragma unroll
    for (int h = 0; h < 2; h++) {
      const float* fr[4];
      float xv[4], av0[4], av1[4], av2[4];
      float bv0[4], bv1[4], bv2[4], bv3[4], bv4[4];
#pragma unroll
      for (int i = 0; i < 4; i++) {
        fr[i] = feats + (size_t)snbL[nl * KNBR + 4 * h + i] * DF;
        xv[i] = fr[i][u];
      }
      if (u < 32) {
#pragma unroll
        for (int i = 0; i < 4; i++) {
          av0[i] = fr[i][64 + 3 * u];
          av1[i] = fr[i][65 + 3 * u];
          av2[i] = fr[i][66 + 3 * u];
        }
        if (u < 16) {
#pragma unroll
          for (int i = 0; i < 4; i++) {
            bv0[i] = fr[i][160 + 5 * u];
            bv1[i] = fr[i][161 + 5 * u];
            bv2[i] = fr[i][162 + 5 * u];
            bv3[i] = fr[i][163 + 5 * u];
            bv4[i] = fr[i][164 + 5 * u];
          }
        }
      }
#pragma unroll
      for (int i = 0; i < 4; i++) {
        const int e = 4 * h + i;
        float X = sevL[(nl * KNBR + e) * 3 + 0];
        float Y = sevL[(nl * KNBR + e) * 3 + 1];
        float Z = sevL[(nl * KNBR + e) * 3 + 2];
        float sxv = S_ * X, syv = S_ * Y, szv = S_ * Z;
        float txv = T_ * X, tyv = T_ * Y, t2z = 2.f * T_ * Z;
        z0x += xv[i] * X;
        z0y += xv[i] * Y;
        z0z += xv[i] * Z;
        if (u < 32) {
          s1 += av0[i] * X + av1[i] * Y + av2[i] * Z;
          p0 += av0[i] * syv + av1[i] * sxv;
          p1 += av0[i] * szv + av2[i] * sxv;
          p2 += av1[i] * szv + av2[i] * syv;
          p3 += av0[i] * sxv - av1[i] * syv;
          p4 += av2[i] * t2z - av0[i] * txv - av1[i] * tyv;
          if (u < 16) {
            q0 += bv0[i] * syv + bv1[i] * szv + bv3[i] * sxv - bv4[i] * txv;
            q1 += bv0[i] * sxv + bv2[i] * szv - bv3[i] * syv - bv4[i] * tyv;
            q2 += bv1[i] * sxv + bv2[i] * syv + bv4[i] * t2z;
          }
        }
      }
    }

    A[32 + 3 * u + 0] = z0x;
    A[32 + 3 * u + 1] = z0y;
    A[32 + 3 * u + 2] = z0z;
    if (u < 32) {
      A[u] = s1;
      float* pp = A + 224 + 5 * u;
      pp[0] = p0; pp[1] = p1; pp[2] = p2; pp[3] = p3; pp[4] = p4;
    }
    if (u < 16) {
      float* qq = A + 384 + 3 * u;
      qq[0] = q0; qq[1] = q1; qq[2] = q2;
    }
    // same-wave LDS RAW: drain DS queue; ds_reads below are memory ops and
    // cannot be hoisted past the "memory" clobber.
    asm volatile("s_waitcnt lgkmcnt(0)" ::: "memory");

    const float* WA = WfL;          // 32x64
    const float* WB = WfL + 2048;   // 64x32
    const float* WC = WfL + 4096;   // 16x32
    const float* WD = WfL + 4608;   // 32x16
    float* orow = out + (size_t)node * DF;

    {  // y0[u] = sum_m S1[m] * WA[m][u]
      float a = 0.f;
#pragma unroll
      for (int m = 0; m < 32; m++) a += A[m] * WA[m * 64 + u];
      orow[u] = a;
    }
#pragma unroll
    for (int m0 = 0; m0 < 96; m0 += 64) {   // y1 flat [w1*3+k]
      int m = m0 + u;
      if (m < 96) {
        int w1 = m / 3, k = m - w1 * 3;
        float a = 0.f;
#pragma unroll
        for (int t = 0; t < 64; t++) a += A[32 + 3 * t + k] * WB[t * 32 + w1];
#pragma unroll
        for (int t = 0; t < 16; t++) a += A[384 + 3 * t + k] * WC[t * 32 + w1];
        orow[64 + m] = a;
      }
    }
#pragma unroll
    for (int m0 = 0; m0 < 80; m0 += 64) {   // y2 flat [w2*5+k]
      int m = m0 + u;
      if (m < 80) {
        int w2 = m / 5, k = m - w2 * 5;
        float a = 0.f;
#pragma unroll
        for (int t = 0; t < 32; t++) a += A[224 + 5 * t + k] * WD[t * 16 + w2];
        orow[160 + m] = a;
      }
    }
    // WAR: this iteration's A reads must not be reordered after next
    // iteration's A writes (compiler fence; DS unit is in-order per wave).
    asm volatile("s_waitcnt lgkmcnt(0)" ::: "memory");
  }
}

// ---------------------------------------------------------------------------
extern "C" void kernel_launch(void* const* d_in, const int* in_sizes, int n_in,
                              void* d_out, int out_size, void* d_ws,
                              size_t ws_size, hipStream_t stream) {
  const float* feats  = (const float*)d_in[0];
  const float* coords = (const float*)d_in[1];
  const float* W1 = (const float*)d_in[2];
  const float* W2 = (const float*)d_in[3];
  const float* W3 = (const float*)d_in[4];
  const float* W4 = (const float*)d_in[5];
  const float* L0 = (const float*)d_in[6];
  const float* L1 = (const float*)d_in[7];
  const float* L2 = (const float*)d_in[8];
  float* out = (float*)d_out;
  (void)d_ws; (void)ws_size;   // workspace no longer needed

  fused_all<<<256, 1024, 0, stream>>>(feats, coords, W1, W2, W3, W4, L0, L1,
                                      L2, out);
}